// Round 1
// baseline (526.870 us; speedup 1.0000x reference)
//
#include <hip/hip_runtime.h>
#include <math.h>

#define TPB 256

// ---------------- degree histogram ----------------
__global__ __launch_bounds__(TPB) void k_deg(const int* __restrict__ ei, int E,
                                             int* __restrict__ od, int* __restrict__ idg) {
    int e = blockIdx.x * TPB + threadIdx.x;
    if (e < E) {
        atomicAdd(&od[ei[e]], 1);        // src out-degree
        atomicAdd(&idg[ei[E + e]], 1);   // dst in-degree
    }
}

// ---------------- norms ----------------
__global__ __launch_bounds__(TPB) void k_norm(const int* __restrict__ od, const int* __restrict__ idg,
                                              float* __restrict__ onr, float* __restrict__ inr, int N) {
    int i = blockIdx.x * TPB + threadIdx.x;
    if (i < N) {
        onr[i] = 1.0f / sqrtf(fmaxf((float)od[i], 1.0f));
        inr[i] = 1.0f / sqrtf(fmaxf((float)idg[i], 1.0f));
    }
}

// ---------------- 2-level exclusive scan for CSR row_ptr ----------------
__global__ __launch_bounds__(TPB) void k_chunk_red(const int* __restrict__ cnt, int N, int* __restrict__ sums) {
    __shared__ int s[TPB];
    int t = threadIdx.x;
    int i = blockIdx.x * TPB + t;
    s[t] = (i < N) ? cnt[i] : 0;
    __syncthreads();
    for (int off = TPB / 2; off > 0; off >>= 1) {
        if (t < off) s[t] += s[t + off];
        __syncthreads();
    }
    if (t == 0) sums[blockIdx.x] = s[0];
}

__global__ __launch_bounds__(TPB) void k_scan_top(const int* __restrict__ sums, int n, int* __restrict__ offs) {
    __shared__ int s[TPB];
    int t = threadIdx.x;
    int v = (t < n) ? sums[t] : 0;
    s[t] = v;
    __syncthreads();
    for (int off = 1; off < TPB; off <<= 1) {
        int x = (t >= off) ? s[t - off] : 0;
        __syncthreads();
        s[t] += x;
        __syncthreads();
    }
    offs[t] = s[t] - v;  // exclusive
}

__global__ __launch_bounds__(TPB) void k_scan_chunk(const int* __restrict__ cnt, int N,
                                                    const int* __restrict__ offs, int* __restrict__ rp) {
    __shared__ int s[TPB];
    int t = threadIdx.x;
    int i = blockIdx.x * TPB + t;
    int v = (i < N) ? cnt[i] : 0;
    s[t] = v;
    __syncthreads();
    for (int off = 1; off < TPB; off <<= 1) {
        int x = (t >= off) ? s[t - off] : 0;
        __syncthreads();
        s[t] += x;
        __syncthreads();
    }
    if (i <= N) rp[i] = s[t] - v + offs[blockIdx.x];
}

// ---------------- CSR fill (order within a row is arbitrary; sum is commutative) ----------------
__global__ __launch_bounds__(TPB) void k_fill(const int* __restrict__ ei, int E,
                                              const int* __restrict__ rp, int* __restrict__ cursor,
                                              const float* __restrict__ onr, const float* __restrict__ inr,
                                              int* __restrict__ col, float* __restrict__ val) {
    int e = blockIdx.x * TPB + threadIdx.x;
    if (e < E) {
        int s = ei[e], d = ei[E + e];
        int pos = atomicAdd(&cursor[d], 1);
        int idx = rp[d] + pos;
        col[idx] = s;
        val[idx] = onr[s] * inr[d];
    }
}

// ---------------- SpMM: one wave per dst row, lane owns 2 of 128 feats ----------------
__global__ __launch_bounds__(TPB) void k_spmm(const float* __restrict__ h,
                                              const int* __restrict__ rp, const int* __restrict__ col,
                                              const float* __restrict__ val,
                                              float* __restrict__ agg, int N) {
    int lane = threadIdx.x & 63;
    int r = blockIdx.x * 4 + (threadIdx.x >> 6);
    if (r >= N) return;
    int e0 = rp[r], e1 = rp[r + 1];
    const float2* hp = (const float2*)h;
    float ax = 0.f, ay = 0.f;
    int e = e0;
    for (; e + 1 < e1; e += 2) {
        int s0 = col[e], s1 = col[e + 1];
        float w0 = val[e], w1 = val[e + 1];
        float2 v0 = hp[(size_t)s0 * 64 + lane];
        float2 v1 = hp[(size_t)s1 * 64 + lane];
        ax += w0 * v0.x + w1 * v1.x;
        ay += w0 * v0.y + w1 * v1.y;
    }
    if (e < e1) {
        int s0 = col[e];
        float w0 = val[e];
        float2 v0 = hp[(size_t)s0 * 64 + lane];
        ax += w0 * v0.x;
        ay += w0 * v0.y;
    }
    float2 o;
    o.x = ax; o.y = ay;
    ((float2*)agg)[(size_t)r * 64 + lane] = o;
}

// ---------------- dense GEMM: C[N,128] = op(A @ W + b)  (MODE0: relu; MODE1: relu(0.6H+0.4.)) ----------------
template <int MODE>
__global__ __launch_bounds__(TPB) void k_gemm128(const float* __restrict__ A,
                                                 const float* __restrict__ W, const float* __restrict__ bias,
                                                 const float* __restrict__ H, float* __restrict__ C, int N) {
    __shared__ float As[64][132];  // stride 132 words: 16B-aligned float4, banks spread
    int t = threadIdx.x;
    int bm = blockIdx.x * 64;
    int bn = blockIdx.y * 64;
#pragma unroll
    for (int rep = 0; rep < 8; ++rep) {
        int idx = rep * TPB + t;
        int i = idx >> 5;
        int k4 = (idx & 31) * 4;
        int row = bm + i;
        float4 v = make_float4(0.f, 0.f, 0.f, 0.f);
        if (row < N) v = *(const float4*)(&A[(size_t)row * 128 + k4]);
        *(float4*)(&As[i][k4]) = v;
    }
    __syncthreads();
    int tx = t & 15, ty = t >> 4;
    int j0 = bn + tx * 4;
    float4 acc[4];
#pragma unroll
    for (int q = 0; q < 4; ++q) acc[q] = make_float4(0.f, 0.f, 0.f, 0.f);
    for (int k = 0; k < 128; k += 4) {
        float4 w0 = *(const float4*)(&W[(size_t)(k + 0) * 128 + j0]);
        float4 w1 = *(const float4*)(&W[(size_t)(k + 1) * 128 + j0]);
        float4 w2 = *(const float4*)(&W[(size_t)(k + 2) * 128 + j0]);
        float4 w3 = *(const float4*)(&W[(size_t)(k + 3) * 128 + j0]);
#pragma unroll
        for (int q = 0; q < 4; ++q) {
            float4 a = *(const float4*)(&As[ty + 16 * q][k]);
            acc[q].x += a.x * w0.x + a.y * w1.x + a.z * w2.x + a.w * w3.x;
            acc[q].y += a.x * w0.y + a.y * w1.y + a.z * w2.y + a.w * w3.y;
            acc[q].z += a.x * w0.z + a.y * w1.z + a.z * w2.z + a.w * w3.z;
            acc[q].w += a.x * w0.w + a.y * w1.w + a.z * w2.w + a.w * w3.w;
        }
    }
    float4 bv = *(const float4*)(&bias[j0]);
#pragma unroll
    for (int q = 0; q < 4; ++q) {
        int row = bm + ty + 16 * q;
        if (row >= N) continue;
        float4 o;
        o.x = acc[q].x + bv.x;
        o.y = acc[q].y + bv.y;
        o.z = acc[q].z + bv.z;
        o.w = acc[q].w + bv.w;
        if (MODE == 1) {
            float4 h = *(const float4*)(&H[(size_t)row * 128 + j0]);
            o.x = 0.6f * h.x + 0.4f * o.x;
            o.y = 0.6f * h.y + 0.4f * o.y;
            o.z = 0.6f * h.z + 0.4f * o.z;
            o.w = 0.6f * h.w + 0.4f * o.w;
        }
        o.x = fmaxf(o.x, 0.f);
        o.y = fmaxf(o.y, 0.f);
        o.z = fmaxf(o.z, 0.f);
        o.w = fmaxf(o.w, 0.f);
        *(float4*)(&C[(size_t)row * 128 + j0]) = o;
    }
}

// ---------------- final layer: out = 0.6*(H2@Ws+bs) + 0.4*(AGG@W3+b3), Nout=64, no relu ----------------
__global__ __launch_bounds__(TPB) void k_final(const float* __restrict__ A, const float* __restrict__ H,
                                               const float* __restrict__ W3, const float* __restrict__ b3,
                                               const float* __restrict__ Ws, const float* __restrict__ bs,
                                               float* __restrict__ C, int N) {
    __shared__ float As[32][132];
    __shared__ float Hs[32][132];
    int t = threadIdx.x;
    int bm = blockIdx.x * 32;
#pragma unroll
    for (int rep = 0; rep < 4; ++rep) {
        int idx = rep * TPB + t;
        int i = idx >> 5;
        int k4 = (idx & 31) * 4;
        int row = bm + i;
        float4 va = make_float4(0.f, 0.f, 0.f, 0.f);
        float4 vh = va;
        if (row < N) {
            va = *(const float4*)(&A[(size_t)row * 128 + k4]);
            vh = *(const float4*)(&H[(size_t)row * 128 + k4]);
        }
        *(float4*)(&As[i][k4]) = va;
        *(float4*)(&Hs[i][k4]) = vh;
    }
    __syncthreads();
    int tx = t & 15, ty = t >> 4;
    int j0 = tx * 4;
    float4 accA[2], accH[2];
#pragma unroll
    for (int q = 0; q < 2; ++q) {
        accA[q] = make_float4(0.f, 0.f, 0.f, 0.f);
        accH[q] = make_float4(0.f, 0.f, 0.f, 0.f);
    }
    for (int k = 0; k < 128; k += 4) {
        float4 u0 = *(const float4*)(&W3[(size_t)(k + 0) * 64 + j0]);
        float4 u1 = *(const float4*)(&W3[(size_t)(k + 1) * 64 + j0]);
        float4 u2 = *(const float4*)(&W3[(size_t)(k + 2) * 64 + j0]);
        float4 u3 = *(const float4*)(&W3[(size_t)(k + 3) * 64 + j0]);
        float4 s0 = *(const float4*)(&Ws[(size_t)(k + 0) * 64 + j0]);
        float4 s1 = *(const float4*)(&Ws[(size_t)(k + 1) * 64 + j0]);
        float4 s2 = *(const float4*)(&Ws[(size_t)(k + 2) * 64 + j0]);
        float4 s3 = *(const float4*)(&Ws[(size_t)(k + 3) * 64 + j0]);
#pragma unroll
        for (int q = 0; q < 2; ++q) {
            float4 a = *(const float4*)(&As[ty + 16 * q][k]);
            float4 h = *(const float4*)(&Hs[ty + 16 * q][k]);
            accA[q].x += a.x * u0.x + a.y * u1.x + a.z * u2.x + a.w * u3.x;
            accA[q].y += a.x * u0.y + a.y * u1.y + a.z * u2.y + a.w * u3.y;
            accA[q].z += a.x * u0.z + a.y * u1.z + a.z * u2.z + a.w * u3.z;
            accA[q].w += a.x * u0.w + a.y * u1.w + a.z * u2.w + a.w * u3.w;
            accH[q].x += h.x * s0.x + h.y * s1.x + h.z * s2.x + h.w * s3.x;
            accH[q].y += h.x * s0.y + h.y * s1.y + h.z * s2.y + h.w * s3.y;
            accH[q].z += h.x * s0.z + h.y * s1.z + h.z * s2.z + h.w * s3.z;
            accH[q].w += h.x * s0.w + h.y * s1.w + h.z * s2.w + h.w * s3.w;
        }
    }
    float4 b3v = *(const float4*)(&b3[j0]);
    float4 bsv = *(const float4*)(&bs[j0]);
#pragma unroll
    for (int q = 0; q < 2; ++q) {
        int row = bm + ty + 16 * q;
        if (row >= N) continue;
        float4 o;
        o.x = 0.6f * (accH[q].x + bsv.x) + 0.4f * (accA[q].x + b3v.x);
        o.y = 0.6f * (accH[q].y + bsv.y) + 0.4f * (accA[q].y + b3v.y);
        o.z = 0.6f * (accH[q].z + bsv.z) + 0.4f * (accA[q].z + b3v.z);
        o.w = 0.6f * (accH[q].w + bsv.w) + 0.4f * (accA[q].w + b3v.w);
        *(float4*)(&C[(size_t)row * 64 + j0]) = o;
    }
}

extern "C" void kernel_launch(void* const* d_in, const int* in_sizes, int n_in,
                              void* d_out, int out_size, void* d_ws, size_t ws_size,
                              hipStream_t stream) {
    const float* x  = (const float*)d_in[0];
    const int*   ei = (const int*)d_in[1];
    const float* W1 = (const float*)d_in[2];
    const float* b1 = (const float*)d_in[3];
    const float* W2 = (const float*)d_in[4];
    const float* b2 = (const float*)d_in[5];
    const float* W3 = (const float*)d_in[6];
    const float* b3 = (const float*)d_in[7];
    const float* Ws = (const float*)d_in[8];
    const float* bs = (const float*)d_in[9];
    float* out = (float*)d_out;

    int N = in_sizes[0] / 128;
    int E = in_sizes[1] / 2;

    char* p = (char*)d_ws;
    auto alloc = [&](size_t bytes) -> char* {
        char* r = p;
        p += (bytes + 255) & ~(size_t)255;
        return r;
    };
    int*   od     = (int*)alloc((size_t)N * 4);
    int*   idg    = (int*)alloc((size_t)N * 4);
    int*   cursor = (int*)alloc((size_t)N * 4);
    int*   csums  = (int*)alloc(4096);
    int*   coffs  = (int*)alloc(4096);
    int*   rp     = (int*)alloc((size_t)(N + 1) * 4);
    float* onr    = (float*)alloc((size_t)N * 4);
    float* inr    = (float*)alloc((size_t)N * 4);
    int*   col    = (int*)alloc((size_t)E * 4);
    float* val    = (float*)alloc((size_t)E * 4);
    float* agg    = (float*)alloc((size_t)N * 128 * 4);
    float* h1     = (float*)alloc((size_t)N * 128 * 4);
    float* h2     = (float*)alloc((size_t)N * 128 * 4);
    (void)ws_size; (void)n_in; (void)out_size;

    int nChunks = (N + TPB - 1) / TPB;  // 196 for N=50000 (must be <= 256)
    int eBlocks = (E + TPB - 1) / TPB;
    int nBlocks = (N + TPB - 1) / TPB;

    hipMemsetAsync(od, 0, (size_t)N * 4, stream);
    hipMemsetAsync(idg, 0, (size_t)N * 4, stream);
    hipMemsetAsync(cursor, 0, (size_t)N * 4, stream);

    k_deg<<<eBlocks, TPB, 0, stream>>>(ei, E, od, idg);
    k_norm<<<nBlocks, TPB, 0, stream>>>(od, idg, onr, inr, N);
    k_chunk_red<<<nChunks, TPB, 0, stream>>>(idg, N, csums);
    k_scan_top<<<1, TPB, 0, stream>>>(csums, nChunks, coffs);
    k_scan_chunk<<<nChunks, TPB, 0, stream>>>(idg, N, coffs, rp);
    k_fill<<<eBlocks, TPB, 0, stream>>>(ei, E, rp, cursor, onr, inr, col, val);

    int spmmBlocks = (N + 3) / 4;
    dim3 gemmGrid((N + 63) / 64, 2);
    int finalBlocks = (N + 31) / 32;

    // layer 0: agg = A_hat @ x ; h1 = relu(agg @ W1 + b1)
    k_spmm<<<spmmBlocks, TPB, 0, stream>>>(x, rp, col, val, agg, N);
    k_gemm128<0><<<gemmGrid, TPB, 0, stream>>>(agg, W1, b1, nullptr, h1, N);
    // layer 1: agg = A_hat @ h1 ; h2 = relu(0.6*h1 + 0.4*(agg @ W2 + b2))
    k_spmm<<<spmmBlocks, TPB, 0, stream>>>(h1, rp, col, val, agg, N);
    k_gemm128<1><<<gemmGrid, TPB, 0, stream>>>(agg, W2, b2, h1, h2, N);
    // layer 2: agg = A_hat @ h2 ; out = 0.6*(h2@Ws+bs) + 0.4*(agg@W3+b3)
    k_spmm<<<spmmBlocks, TPB, 0, stream>>>(h2, rp, col, val, agg, N);
    k_final<<<finalBlocks, TPB, 0, stream>>>(agg, h2, W3, b3, Ws, bs, out, N);
}